// Round 5
// baseline (261.921 us; speedup 1.0000x reference)
//
#include <hip/hip_runtime.h>
#include <limits.h>
#include <math.h>
#include <stdint.h>

// Problem constants (fixed by setup_inputs): x[128][262144] fp32, topk=5.
#define BROWS 128
#define NCOLS (256 * 32 * 32)        // 262144 elements per row
#define K 5
#define BPR 8                        // blocks per row -> 1024 blocks, 4/CU
#define TPB 256                      // threads per block
#define CHUNK (NCOLS / BPR)          // 32768 elements per block
#define F4T (CHUNK / 4 / TPB)        // 32 float4 per thread
#define BATCH 8
#define NBATCH (F4T / BATCH)         // 4

typedef float v4f __attribute__((ext_vector_type(4)));  // native vec for nt-store

// ---- packed 64-bit candidate key: [sortable_f32 : 32][~index : 32] ----
// bigger key == better (value desc, then index asc) -> matches jax.lax.top_k.
__device__ __forceinline__ uint64_t make_key(float f, uint32_t idx) {
    uint32_t u = __float_as_uint(f);
    u = (u & 0x80000000u) ? ~u : (u | 0x80000000u);   // monotone fp32 -> u32
    return ((uint64_t)u << 32) | (uint32_t)(~idx);
}
__device__ __forceinline__ float key_val(uint64_t k) {
    uint32_t u = (uint32_t)(k >> 32);
    u = (u & 0x80000000u) ? (u ^ 0x80000000u) : ~u;
    return __uint_as_float(u);
}
__device__ __forceinline__ uint32_t key_idx(uint64_t k) {
    return ~(uint32_t)k;
}

// Sentinel: decodes to exactly -inf via key_val (key==0 would decode to NaN
// and poison the vmin guard -- that was round 4's bug).
#define KEY_NEG_INF 0x007FFFFF00000000ULL  // make_key(-INFINITY, 0xFFFFFFFF)

// Insert into sorted-descending top-K key list. Fully unrolled, stays in VGPRs.
__device__ __forceinline__ void insert5(uint64_t (&key)[K], uint64_t c) {
    if (c > key[K - 1]) {
        key[K - 1] = c;
#pragma unroll
        for (int s = K - 1; s > 0; --s) {
            if (key[s] > key[s - 1]) {
                uint64_t t = key[s]; key[s] = key[s - 1]; key[s - 1] = t;
            }
        }
    }
}

__device__ __forceinline__ void wave_reduce5(uint64_t (&key)[K]) {
#pragma unroll
    for (int off = 1; off < 64; off <<= 1) {
        uint64_t ok[K];
#pragma unroll
        for (int k = 0; k < K; ++k)
            ok[k] = __shfl_xor((unsigned long long)key[k], off, 64);
#pragma unroll
        for (int k = 0; k < K; ++k) insert5(key, ok[k]);
    }
}

// Kernel 1: stream x (read) + zero out (nontemporal write) in one pass;
// per-block top-5 keys -> workspace. Software-pipelined batches of 8 float4.
__global__ __launch_bounds__(TPB) void wta_scan(const float* __restrict__ x,
                                                float* __restrict__ out,
                                                uint64_t* __restrict__ wsk) {
    const int gb  = blockIdx.x;
    const int row = gb / BPR;
    const int blk = gb % BPR;
    const size_t base = (size_t)row * NCOLS + (size_t)blk * CHUNK;
    const float4* __restrict__ x4 = (const float4*)(x + base);
    v4f* __restrict__ o4 = (v4f*)(out + base);
    const int t = threadIdx.x;

    uint64_t key[K];
#pragma unroll
    for (int k = 0; k < K; ++k) key[k] = KEY_NEG_INF;
    float vmin = -INFINITY;                        // value of key[K-1]

    const v4f z = {0.f, 0.f, 0.f, 0.f};

    float4 cur[BATCH], nxt[BATCH];
#pragma unroll
    for (int j = 0; j < BATCH; ++j) cur[j] = x4[t + j * TPB];

#pragma unroll
    for (int b = 0; b < NBATCH; ++b) {
        // prefetch next batch (independent of processing below)
        if (b + 1 < NBATCH) {
#pragma unroll
            for (int j = 0; j < BATCH; ++j)
                nxt[j] = x4[t + ((b + 1) * BATCH + j) * TPB];
        }
        // streaming zero-stores for this batch's region
#pragma unroll
        for (int j = 0; j < BATCH; ++j)
            __builtin_nontemporal_store(z, &o4[t + (b * BATCH + j) * TPB]);
        // process current batch: fast path = 3 v_max + 1 v_cmp per float4
#pragma unroll
        for (int j = 0; j < BATCH; ++j) {
            const float4 d = cur[j];
            const float m = fmaxf(fmaxf(d.x, d.y), fmaxf(d.z, d.w));
            if (m >= vmin) {   // superset of insert condition
                const uint32_t e = (uint32_t)(blk * CHUNK) +
                                   (uint32_t)(t + (b * BATCH + j) * TPB) * 4u;
                insert5(key, make_key(d.x, e + 0));
                insert5(key, make_key(d.y, e + 1));
                insert5(key, make_key(d.z, e + 2));
                insert5(key, make_key(d.w, e + 3));
                vmin = key_val(key[K - 1]);
            }
        }
#pragma unroll
        for (int j = 0; j < BATCH; ++j) cur[j] = nxt[j];
    }

    wave_reduce5(key);

    __shared__ uint64_t sk[TPB / 64][K];
    const int wave = t >> 6, lane = t & 63;
    if (lane == 0) {
#pragma unroll
        for (int k = 0; k < K; ++k) sk[wave][k] = key[k];
    }
    __syncthreads();
    if (t == 0) {
#pragma unroll
        for (int w = 1; w < TPB / 64; ++w)
#pragma unroll
            for (int k = 0; k < K; ++k) insert5(key, sk[w][k]);
#pragma unroll
        for (int k = 0; k < K; ++k) wsk[gb * K + k] = key[k];
    }
}

// Kernel 2: per row, merge BPR*K=40 candidate keys, scatter five 1.0f stores.
__global__ __launch_bounds__(64) void wta_final(const uint64_t* __restrict__ wsk,
                                                float* __restrict__ out) {
    const int row  = blockIdx.x;
    const int lane = threadIdx.x;

    uint64_t key[K];
#pragma unroll
    for (int k = 0; k < K; ++k) key[k] = KEY_NEG_INF;

    const int ncand = BPR * K; // 40
    if (lane < ncand) insert5(key, wsk[row * ncand + lane]);

    wave_reduce5(key);

    if (lane == 0) {
#pragma unroll
        for (int k = 0; k < K; ++k)
            out[(size_t)row * NCOLS + key_idx(key[k])] = 1.0f;
    }
}

extern "C" void kernel_launch(void* const* d_in, const int* in_sizes, int n_in,
                              void* d_out, int out_size, void* d_ws, size_t ws_size,
                              hipStream_t stream) {
    const float* x = (const float*)d_in[0];
    // d_in[1] is topk (==5 always); K is compile-time.
    float* out = (float*)d_out;
    uint64_t* wsk = (uint64_t*)d_ws;   // 1024*5 u64 keys = 40 KB

    wta_scan<<<BROWS * BPR, TPB, 0, stream>>>(x, out, wsk);
    wta_final<<<BROWS, 64, 0, stream>>>(wsk, out);
}

// Round 6
// 260.665 us; speedup vs baseline: 1.0048x; 1.0048x over previous
//
#include <hip/hip_runtime.h>
#include <limits.h>
#include <math.h>
#include <stdint.h>

// Problem constants (fixed by setup_inputs): x[128][262144] fp32, topk=5.
#define BROWS 128
#define NCOLS (256 * 32 * 32)        // 262144 elements per row
#define K 5
#define BPR 32                       // blocks per row -> 4096 scan blocks
#define TPB 256                      // threads per block
#define CHUNK (NCOLS / BPR)          // 8192 elements per block
#define F4T (CHUNK / 4 / TPB)        // 8 float4 per thread

#define TOTAL_F4 ((size_t)BROWS * NCOLS / 4)   // 8,388,608 float4
#define FILL_BLOCKS 4096
#define FILL_F4T (TOTAL_F4 / FILL_BLOCKS / TPB) // 8 float4 per thread

typedef float v4f __attribute__((ext_vector_type(4)));  // native vec for nt-store

// ---- packed 64-bit candidate key: [sortable_f32 : 32][~index : 32] ----
// bigger key == better (value desc, then index asc) -> matches jax.lax.top_k.
__device__ __forceinline__ uint64_t make_key(float f, uint32_t idx) {
    uint32_t u = __float_as_uint(f);
    u = (u & 0x80000000u) ? ~u : (u | 0x80000000u);   // monotone fp32 -> u32
    return ((uint64_t)u << 32) | (uint32_t)(~idx);
}
__device__ __forceinline__ float key_val(uint64_t k) {
    uint32_t u = (uint32_t)(k >> 32);
    u = (u & 0x80000000u) ? (u ^ 0x80000000u) : ~u;
    return __uint_as_float(u);
}
__device__ __forceinline__ uint32_t key_idx(uint64_t k) {
    return ~(uint32_t)k;
}

// Sentinel: decodes to exactly -inf via key_val (key==0 decodes to NaN and
// poisons the vmin guard -- round 4's bug).
#define KEY_NEG_INF 0x007FFFFF00000000ULL  // make_key(-INFINITY, 0xFFFFFFFF)

__device__ __forceinline__ void insert5(uint64_t (&key)[K], uint64_t c) {
    if (c > key[K - 1]) {
        key[K - 1] = c;
#pragma unroll
        for (int s = K - 1; s > 0; --s) {
            if (key[s] > key[s - 1]) {
                uint64_t t = key[s]; key[s] = key[s - 1]; key[s - 1] = t;
            }
        }
    }
}

__device__ __forceinline__ void wave_reduce5(uint64_t (&key)[K]) {
#pragma unroll
    for (int off = 1; off < 64; off <<= 1) {
        uint64_t ok[K];
#pragma unroll
        for (int k = 0; k < K; ++k)
            ok[k] = __shfl_xor((unsigned long long)key[k], off, 64);
#pragma unroll
        for (int k = 0; k < K; ++k) insert5(key, ok[k]);
    }
}

// Kernel A: pure read-stream scan. Loads 8 float4 into registers, then
// guard-processes (fast path: 3 v_max + 1 v_cmp per float4).
__global__ __launch_bounds__(TPB) void wta_scan(const float* __restrict__ x,
                                                uint64_t* __restrict__ wsk) {
    const int gb  = blockIdx.x;
    const int row = gb / BPR;
    const int blk = gb % BPR;
    const size_t base = (size_t)row * NCOLS + (size_t)blk * CHUNK;
    const float4* __restrict__ x4 = (const float4*)(x + base);
    const int t = threadIdx.x;

    float4 r[F4T];
#pragma unroll
    for (int i = 0; i < F4T; ++i) r[i] = x4[t + i * TPB];

    uint64_t key[K];
#pragma unroll
    for (int k = 0; k < K; ++k) key[k] = KEY_NEG_INF;
    float vmin = -INFINITY;

#pragma unroll
    for (int i = 0; i < F4T; ++i) {
        const float4 d = r[i];
        const float m = fmaxf(fmaxf(d.x, d.y), fmaxf(d.z, d.w));
        if (m >= vmin) {   // superset of insert condition
            const uint32_t e = (uint32_t)(blk * CHUNK) +
                               (uint32_t)(t + i * TPB) * 4u;
            insert5(key, make_key(d.x, e + 0));
            insert5(key, make_key(d.y, e + 1));
            insert5(key, make_key(d.z, e + 2));
            insert5(key, make_key(d.w, e + 3));
            vmin = key_val(key[K - 1]);
        }
    }

    wave_reduce5(key);

    __shared__ uint64_t sk[TPB / 64][K];
    const int wave = t >> 6, lane = t & 63;
    if (lane == 0) {
#pragma unroll
        for (int k = 0; k < K; ++k) sk[wave][k] = key[k];
    }
    __syncthreads();
    if (t == 0) {
#pragma unroll
        for (int w = 1; w < TPB / 64; ++w)
#pragma unroll
            for (int k = 0; k < K; ++k) insert5(key, sk[w][k]);
#pragma unroll
        for (int k = 0; k < K; ++k) wsk[gb * K + k] = key[k];
    }
}

// Kernel B: pure write-stream zero fill (nontemporal, memset-style).
__global__ __launch_bounds__(TPB) void wta_fill(float* __restrict__ out) {
    v4f* __restrict__ o4 = (v4f*)out;
    const size_t base = (size_t)blockIdx.x * (TPB * FILL_F4T) + threadIdx.x;
    const v4f z = {0.f, 0.f, 0.f, 0.f};
#pragma unroll
    for (int i = 0; i < FILL_F4T; ++i)
        __builtin_nontemporal_store(z, &o4[base + (size_t)i * TPB]);
}

// Kernel C: per row, merge BPR*K=160 candidate keys, scatter five 1.0f stores.
__global__ __launch_bounds__(64) void wta_final(const uint64_t* __restrict__ wsk,
                                                float* __restrict__ out) {
    const int row  = blockIdx.x;
    const int lane = threadIdx.x;

    uint64_t key[K];
#pragma unroll
    for (int k = 0; k < K; ++k) key[k] = KEY_NEG_INF;

    const int ncand = BPR * K; // 160
    for (int c = lane; c < ncand; c += 64)
        insert5(key, wsk[row * ncand + c]);

    wave_reduce5(key);

    if (lane == 0) {
#pragma unroll
        for (int k = 0; k < K; ++k)
            out[(size_t)row * NCOLS + key_idx(key[k])] = 1.0f;
    }
}

extern "C" void kernel_launch(void* const* d_in, const int* in_sizes, int n_in,
                              void* d_out, int out_size, void* d_ws, size_t ws_size,
                              hipStream_t stream) {
    const float* x = (const float*)d_in[0];
    // d_in[1] is topk (==5 always); K is compile-time.
    float* out = (float*)d_out;
    uint64_t* wsk = (uint64_t*)d_ws;   // 4096*5 u64 keys = 160 KB

    wta_scan<<<BROWS * BPR, TPB, 0, stream>>>(x, wsk);      // read stream
    wta_fill<<<FILL_BLOCKS, TPB, 0, stream>>>(out);         // write stream
    wta_final<<<BROWS, 64, 0, stream>>>(wsk, out);          // tiny scatter
}

// Round 7
// 253.452 us; speedup vs baseline: 1.0334x; 1.0285x over previous
//
#include <hip/hip_runtime.h>
#include <limits.h>
#include <math.h>
#include <stdint.h>

// Problem constants (fixed by setup_inputs): x[128][262144] fp32, topk=5.
#define BROWS 128
#define NCOLS (256 * 32 * 32)        // 262144 elements per row
#define K 5
#define BPR 16                       // groups (blocks) per row -> 2048 blocks
#define TPB 256
#define CHUNK (NCOLS / BPR)          // 16384 elements per group
#define F4T (CHUNK / 4 / TPB)        // 16 float4 per thread
#define CAP 256                      // per-row candidate capacity (expect ~10)

typedef float v4f __attribute__((ext_vector_type(4)));

// ---- packed 64-bit candidate key: [sortable_f32 : 32][~index : 32] ----
// bigger key == better (value desc, then index asc) -> matches jax.lax.top_k.
__device__ __forceinline__ uint64_t make_key(float f, uint32_t idx) {
    uint32_t u = __float_as_uint(f);
    u = (u & 0x80000000u) ? ~u : (u | 0x80000000u);   // monotone fp32 -> u32
    return ((uint64_t)u << 32) | (uint32_t)(~idx);
}
__device__ __forceinline__ uint32_t key_idx(uint64_t k) { return ~(uint32_t)k; }

#define KEY_NEG_INF 0x007FFFFF00000000ULL  // make_key(-INFINITY, 0xFFFFFFFF)

__device__ __forceinline__ void insert5(uint64_t (&key)[K], uint64_t c) {
    if (c > key[K - 1]) {
        key[K - 1] = c;
#pragma unroll
        for (int s = K - 1; s > 0; --s) {
            if (key[s] > key[s - 1]) {
                uint64_t t = key[s]; key[s] = key[s - 1]; key[s - 1] = t;
            }
        }
    }
}

__device__ __forceinline__ void wave_reduce5(uint64_t (&key)[K]) {
#pragma unroll
    for (int off = 1; off < 64; off <<= 1) {
        uint64_t ok[K];
#pragma unroll
        for (int k = 0; k < K; ++k)
            ok[k] = __shfl_xor((unsigned long long)key[k], off, 64);
#pragma unroll
        for (int k = 0; k < K; ++k) insert5(key, ok[k]);
    }
}

// float top-5 insert (values only, for the threshold)
__device__ __forceinline__ void insert5f(float (&v)[K], float c) {
    if (c > v[K - 1]) {
        v[K - 1] = c;
#pragma unroll
        for (int s = K - 1; s > 0; --s) {
            if (v[s] > v[s - 1]) { float t = v[s]; v[s] = v[s - 1]; v[s - 1] = t; }
        }
    }
}

// K1: branch-free group-max scan. Pure read stream, loads fully pipelineable.
__global__ __launch_bounds__(TPB) void wta_gmax(const float* __restrict__ x,
                                                float* __restrict__ gmax) {
    const int gb = blockIdx.x;
    const float4* __restrict__ x4 = (const float4*)(x + (size_t)gb * CHUNK);
    const int t = threadIdx.x;

    float m = -INFINITY;
#pragma unroll
    for (int i = 0; i < F4T; ++i) {
        const float4 d = x4[t + i * TPB];
        m = fmaxf(m, fmaxf(fmaxf(d.x, d.y), fmaxf(d.z, d.w)));
    }
#pragma unroll
    for (int off = 1; off < 64; off <<= 1)
        m = fmaxf(m, __shfl_xor(m, off, 64));

    __shared__ float sm[TPB / 64];
    if ((t & 63) == 0) sm[t >> 6] = m;
    __syncthreads();
    if (t == 0)
        gmax[gb] = fmaxf(fmaxf(sm[0], sm[1]), fmaxf(sm[2], sm[3]));
}

// K2: per row, T = 5th-largest of the 16 group maxes; zero the atomic counters.
__global__ __launch_bounds__(64) void wta_thresh(const float* __restrict__ gmax,
                                                 float* __restrict__ T,
                                                 int* __restrict__ cnt) {
    const int row = blockIdx.x, lane = threadIdx.x;
    float v[K];
#pragma unroll
    for (int k = 0; k < K; ++k) v[k] = -INFINITY;
    if (lane < BPR) insert5f(v, gmax[row * BPR + lane]);
#pragma unroll
    for (int off = 1; off < 64; off <<= 1) {
        float ov[K];
#pragma unroll
        for (int k = 0; k < K; ++k) ov[k] = __shfl_xor(v[k], off, 64);
#pragma unroll
        for (int k = 0; k < K; ++k) insert5f(v, ov[k]);
    }
    if (lane == 0) { T[row] = v[K - 1]; cnt[row] = 0; }
}

// K3: fused zero-fill (nt stores) + threshold filter. Guard compares against a
// loop-invariant scalar -> no loop-carried dep, survivors ~1e-4 so the wave
// fast path is real. Survivors pushed to per-row candidate list via atomics.
__global__ __launch_bounds__(TPB) void wta_fillfilter(const float* __restrict__ x,
                                                      float* __restrict__ out,
                                                      const float* __restrict__ T,
                                                      int* __restrict__ cnt,
                                                      uint64_t* __restrict__ cand) {
    const int gb  = blockIdx.x;
    const int row = gb / BPR;
    const int blk = gb % BPR;
    const size_t base = (size_t)gb * CHUNK;
    const float4* __restrict__ x4 = (const float4*)(x + base);
    v4f* __restrict__ o4 = (v4f*)(out + base);
    const int t = threadIdx.x;
    const float Trow = T[row];      // wave-uniform
    const v4f z = {0.f, 0.f, 0.f, 0.f};

#pragma unroll
    for (int h = 0; h < 2; ++h) {   // two half-batches of 8 for bounded VGPRs
        float4 r[F4T / 2];
#pragma unroll
        for (int j = 0; j < F4T / 2; ++j)
            r[j] = x4[t + (h * (F4T / 2) + j) * TPB];
#pragma unroll
        for (int j = 0; j < F4T / 2; ++j)
            __builtin_nontemporal_store(z, &o4[t + (h * (F4T / 2) + j) * TPB]);
#pragma unroll
        for (int j = 0; j < F4T / 2; ++j) {
            const float4 d = r[j];
            const float m = fmaxf(fmaxf(d.x, d.y), fmaxf(d.z, d.w));
            if (m >= Trow) {        // rare: ~10 hits per 262144 elements
                const uint32_t e = (uint32_t)blk * CHUNK +
                                   (uint32_t)(t + (h * (F4T / 2) + j) * TPB) * 4u;
                const float vs[4] = {d.x, d.y, d.z, d.w};
#pragma unroll
                for (int c = 0; c < 4; ++c) {
                    if (vs[c] >= Trow) {
                        const int slot = atomicAdd(&cnt[row], 1);
                        if (slot < CAP) cand[row * CAP + slot] = make_key(vs[c], e + c);
                    }
                }
            }
        }
    }
}

// K4: per row, top-5 of the <=CAP survivors, scatter five 1.0f stores.
__global__ __launch_bounds__(64) void wta_final(const int* __restrict__ cnt,
                                                const uint64_t* __restrict__ cand,
                                                float* __restrict__ out) {
    const int row = blockIdx.x, lane = threadIdx.x;
    const int n = min(cnt[row], CAP);

    uint64_t key[K];
#pragma unroll
    for (int k = 0; k < K; ++k) key[k] = KEY_NEG_INF;
    for (int c = lane; c < n; c += 64) insert5(key, cand[row * CAP + c]);

    wave_reduce5(key);

    if (lane == 0) {
#pragma unroll
        for (int k = 0; k < K; ++k)
            if (key[k] != KEY_NEG_INF)
                out[(size_t)row * NCOLS + key_idx(key[k])] = 1.0f;
    }
}

extern "C" void kernel_launch(void* const* d_in, const int* in_sizes, int n_in,
                              void* d_out, int out_size, void* d_ws, size_t ws_size,
                              hipStream_t stream) {
    const float* x = (const float*)d_in[0];
    float* out = (float*)d_out;

    // ws layout: cand (128*256 u64) | gmax (2048 f32) | T (128 f32) | cnt (128 i32)
    uint64_t* cand = (uint64_t*)d_ws;
    float* gmax = (float*)(cand + (size_t)BROWS * CAP);
    float* T    = gmax + BROWS * BPR;
    int*   cnt  = (int*)(T + BROWS);

    wta_gmax<<<BROWS * BPR, TPB, 0, stream>>>(x, gmax);
    wta_thresh<<<BROWS, 64, 0, stream>>>(gmax, T, cnt);
    wta_fillfilter<<<BROWS * BPR, TPB, 0, stream>>>(x, out, T, cnt, cand);
    wta_final<<<BROWS, 64, 0, stream>>>(cnt, cand, out);
}